// Round 6
// baseline (288.904 us; speedup 1.0000x reference)
//
#include <hip/hip_runtime.h>

// HistoryAttention, restructured:
//   A2  = Wk^T Wq                  (so xA = x@(Wq^T Wk) = x · A2^T)
//   xA  = x_bf16 · A2^T            [16384,1024]
//   scores[b,t,h] = (xA[b,t]·hist[t,h] + hist[t,h]·u3)/32 + log(decay[31-h]+1e-10)
//   AH[b,t] = sum_h softmax(scores)·hist[t,h]
//   out = [AH | x] · [Wvo | Wo]^T + (Wo·bv + bo),  Wvo = Wo·Wv
// Big GEMMs: 256x256/BK=64, A 3-buffer ring (2-tile prefetch) + B 2-buffer,
// counted vmcnt(4) boundaries (T4). 160KB LDS/block.

#define BB 8
#define TT 2048
#define DD 1024
#define HH 32

typedef __attribute__((ext_vector_type(8))) short short8;
typedef __attribute__((ext_vector_type(4))) float f32x4;

__device__ __forceinline__ short f2b(float f) {
  unsigned u = __float_as_uint(f);
  unsigned r = u + 0x7fffu + ((u >> 16) & 1u);
  return (short)(r >> 16);
}

__device__ __forceinline__ void gload_lds16(const void* g, void* l) {
  __builtin_amdgcn_global_load_lds(
      (const __attribute__((address_space(1))) void*)g,
      (__attribute__((address_space(3))) void*)l, 16, 0, 0);
}

// ---------- fused prep: weight transposes, bf16 converts, u3, bfinal ----------
__global__ __launch_bounds__(256) void k_prep(
    const float* __restrict__ x, const float* __restrict__ Wq,
    const float* __restrict__ bq, const float* __restrict__ Wk,
    const float* __restrict__ Wv, const float* __restrict__ bv,
    const float* __restrict__ Wo, const float* __restrict__ bo,
    short* __restrict__ WqT, short* __restrict__ WkT, short* __restrict__ WvT,
    short* __restrict__ CC, short* __restrict__ WB, float* __restrict__ u3,
    float* __restrict__ bfin) {
  const int b = blockIdx.x;
  const int tid = threadIdx.x;
  if (b < 3072) {
    __shared__ float tile[32][33];
    const int z = b >> 10, rem = b & 1023;
    const float* src = z == 0 ? Wq : (z == 1 ? Wk : Wv);
    short* dst = z == 0 ? WqT : (z == 1 ? WkT : WvT);
    const int bx = (rem & 31) * 32, by = (rem >> 5) * 32;
    const int tx = tid & 31, ty = tid >> 5;
#pragma unroll
    for (int k = 0; k < 4; k++)
      tile[ty + 8 * k][tx] = src[(size_t)(by + ty + 8 * k) * DD + bx + tx];
    __syncthreads();
#pragma unroll
    for (int k = 0; k < 4; k++)
      dst[(size_t)(bx + ty + 8 * k) * DD + by + tx] = f2b(tile[tx][ty + 8 * k]);
  } else if (b < 11776) {
    const bool isx = b < 11264;
    const float* src = isx ? x : Wo;
    short* dst = isx ? CC : WB;
    size_t i = (((size_t)(b - (isx ? 3072 : 11264))) * 256 + tid) * 8;
    float4 a = *(const float4*)(src + i);
    float4 c = *(const float4*)(src + i + 4);
    short8 o;
    o[0] = f2b(a.x); o[1] = f2b(a.y); o[2] = f2b(a.z); o[3] = f2b(a.w);
    o[4] = f2b(c.x); o[5] = f2b(c.y); o[6] = f2b(c.z); o[7] = f2b(c.w);
    size_t r = i >> 10, cc = i & 1023;
    *(short8*)(dst + r * 2048 + 1024 + cc) = o;
  } else if (b < 11780) {
    const int d = (b - 11776) * 256 + tid;
    float a0 = 0, a1 = 0, a2 = 0, a3 = 0;
    for (int j = 0; j < DD; j += 4) {
      a0 = fmaf(Wk[(size_t)(j + 0) * DD + d], bq[j + 0], a0);
      a1 = fmaf(Wk[(size_t)(j + 1) * DD + d], bq[j + 1], a1);
      a2 = fmaf(Wk[(size_t)(j + 2) * DD + d], bq[j + 2], a2);
      a3 = fmaf(Wk[(size_t)(j + 3) * DD + d], bq[j + 3], a3);
    }
    u3[d] = (a0 + a1) + (a2 + a3);
  } else {
    const int j = b - 11780;
    float acc = 0.f;
    for (int d = tid; d < DD; d += 256) acc = fmaf(Wo[(size_t)j * DD + d], bv[d], acc);
#pragma unroll
    for (int off = 32; off >= 1; off >>= 1) acc += __shfl_down(acc, off);
    __shared__ float p[4];
    if ((tid & 63) == 0) p[tid >> 6] = acc;
    __syncthreads();
    if (tid == 0) bfin[j] = p[0] + p[1] + p[2] + p[3] + bo[j];
  }
}

// ---------- batched 64x64-tile GEMM for the two 1024^3 weight products ----------
__global__ __launch_bounds__(256) void k_gemm64x2(const short* __restrict__ WkT,
                                                  const short* __restrict__ WqT,
                                                  short* __restrict__ A2,
                                                  const short* __restrict__ WoB,
                                                  const short* __restrict__ WvT,
                                                  short* __restrict__ WB) {
  __shared__ short At[64 * 32];
  __shared__ short Bt[64 * 32];
  const short* A; const short* B; short* C; int lda, ldb, ldc;
  if (blockIdx.z == 0) {
    A = WkT; lda = 1024; B = WqT; ldb = 1024; C = A2; ldc = 1024;
  } else {
    A = WoB; lda = 2048; B = WvT; ldb = 1024; C = WB; ldc = 2048;
  }
  const int tid = threadIdx.x;
  const int w = tid >> 6, l = tid & 63;
  const int wm = w >> 1, wn = w & 1;
  const int lrow = l & 15, lk = l >> 4;
  const size_t m0 = (size_t)blockIdx.x * 64;
  const size_t n0 = (size_t)blockIdx.y * 64;

  f32x4 acc[2][2];
#pragma unroll
  for (int i = 0; i < 2; i++)
#pragma unroll
    for (int j = 0; j < 2; j++) acc[i][j] = (f32x4){0.f, 0.f, 0.f, 0.f};

  const unsigned ubase = (unsigned)((tid & ~63) * 16);
  const int r0 = tid >> 2, kc = tid & 3;

  for (int k0 = 0; k0 < 1024; k0 += 32) {
    __syncthreads();
    gload_lds16(A + (m0 + r0) * lda + k0 + kc * 8, (char*)At + ubase);
    gload_lds16(B + (n0 + r0) * ldb + k0 + kc * 8, (char*)Bt + ubase);
    __syncthreads();
    short8 af[2], bfv[2];
    const int aoff = (wm * 32 + lrow) * 32 + lk * 8;
    const int boff = (wn * 32 + lrow) * 32 + lk * 8;
#pragma unroll
    for (int mi = 0; mi < 2; mi++) af[mi] = *(const short8*)(At + aoff + mi * 512);
#pragma unroll
    for (int ni = 0; ni < 2; ni++) bfv[ni] = *(const short8*)(Bt + boff + ni * 512);
#pragma unroll
    for (int mi = 0; mi < 2; mi++)
#pragma unroll
      for (int ni = 0; ni < 2; ni++)
        acc[mi][ni] = __builtin_amdgcn_mfma_f32_16x16x32_bf16(af[mi], bfv[ni],
                                                              acc[mi][ni], 0, 0, 0);
  }

#pragma unroll
  for (int ni = 0; ni < 2; ni++) {
    const size_t col = n0 + wn * 32 + ni * 16 + lrow;
#pragma unroll
    for (int mi = 0; mi < 2; mi++) {
#pragma unroll
      for (int q = 0; q < 4; q++) {
        const size_t row = m0 + wm * 32 + mi * 16 + lk * 4 + q;
        C[row * ldc + col] = f2b(acc[mi][ni][q]);
      }
    }
  }
}

// ---------- 256x256 / BK=64, 8 waves, st_16x32 swizzle, counted-vmcnt pipeline ----
// LDS 160KB: A ring 3x32KB at 0 (2-tile prefetch), B ring 2x32KB at +96KB.
// Issue order per tile t (phase 0): B(t+1) then A(t+2). Boundary: vmcnt(4)
// (allow only A(t+2) in flight; in-order vmcnt => A(t+1),B(t+1) drained).
template <bool OUT_BF16>
__global__ __launch_bounds__(512) void k_gemm256(const short* __restrict__ A, int lda,
                                                 const short* __restrict__ B, int ldb,
                                                 void* __restrict__ Cv, int ldc, int K,
                                                 const float* __restrict__ bias,
                                                 int nblocks) {
  extern __shared__ char lds[];
  char* ldsA = lds;            // 3 x 32KB
  char* ldsB = lds + 98304;    // 2 x 32KB
  const int tid = threadIdx.x;
  const int w = tid >> 6;
  const int l = tid & 63;
  const int wm = w >> 2, wn = w & 3;
  const int lrow = l & 15, lk = l >> 4;

  // XCD-aware swizzle (gridDim.x % 8 == 0); nb fast within each XCD's chunk
  const int nwg = gridDim.x;
  const int cpx = nwg >> 3;
  const int lin = blockIdx.x;
  const int wg = (lin & 7) * cpx + (lin >> 3);
  const int mb = wg / nblocks;
  const int nb = wg % nblocks;
  const size_t m0 = (size_t)mb * 256;
  const size_t n0 = (size_t)nb * 256;

  // staging decode: physical q = tid*16 -> logical = q ^ ((q>>9&1)<<5)
  const int r0 = tid >> 3;
  const int r1 = 64 + (tid >> 3);
  const int kk0 = (((tid & 7) * 16) ^ (((tid >> 5) & 1) << 5)) >> 1;
  const short* pA00 = A + (m0 + r0) * lda + kk0;
  const short* pA01 = A + (m0 + r1) * lda + kk0;
  const short* pA10 = A + (m0 + 128 + r0) * lda + kk0;
  const short* pA11 = A + (m0 + 128 + r1) * lda + kk0;
  const short* pB00 = B + (n0 + r0) * ldb + kk0;
  const short* pB01 = B + (n0 + r1) * ldb + kk0;
  const short* pB10 = B + (n0 + 128 + r0) * ldb + kk0;
  const short* pB11 = B + (n0 + 128 + r1) * ldb + kk0;
  const unsigned wb16 = (unsigned)((tid & ~63) * 16);

  f32x4 acc[8][4];
#pragma unroll
  for (int i = 0; i < 8; i++)
#pragma unroll
    for (int j = 0; j < 4; j++) acc[i][j] = (f32x4){0.f, 0.f, 0.f, 0.f};

  const int NT = K >> 6;

#define STAGE_A(bufsel, koff)                                     \
  do {                                                            \
    char* ab_ = ldsA + (bufsel) * 32768;                          \
    gload_lds16(pA00 + (koff), ab_ + wb16);                       \
    gload_lds16(pA01 + (koff), ab_ + 8192 + wb16);                \
    gload_lds16(pA10 + (koff), ab_ + 16384 + wb16);               \
    gload_lds16(pA11 + (koff), ab_ + 24576 + wb16);               \
  } while (0)
#define STAGE_B(bufsel, koff)                                     \
  do {                                                            \
    char* bb_ = ldsB + (bufsel) * 32768;                          \
    gload_lds16(pB00 + (koff), bb_ + wb16);                       \
    gload_lds16(pB01 + (koff), bb_ + 8192 + wb16);                \
    gload_lds16(pB10 + (koff), bb_ + 16384 + wb16);               \
    gload_lds16(pB11 + (koff), bb_ + 24576 + wb16);               \
  } while (0)

  // prologue: B0, A0, A1 in flight; wait for B0,A0 (allow A1 outstanding)
  STAGE_B(0, 0);
  STAGE_A(0, 0);
  if (NT > 1) {
    STAGE_A(1, 64);
    asm volatile("s_waitcnt vmcnt(4)" ::: "memory");
  } else {
    asm volatile("s_waitcnt vmcnt(0)" ::: "memory");
  }
  __syncthreads();

  const int aswz = ((lrow >> 2) & 1) << 5;  // st_16x32: flip bit5 when row bit2 set

  for (int kt = 0; kt < NT; ++kt) {
    const char* Ab = ldsA + (kt % 3) * 32768 + wm * 16384;
    const char* Bb = ldsB + (kt & 1) * 32768 + (wn >> 1) * 16384;
    const int bro = (wn & 1) * 64;

    short8 bfr[4][2];
#pragma unroll
    for (int fn = 0; fn < 4; fn++)
#pragma unroll
      for (int ks = 0; ks < 2; ks++) {
        const int ph = (((bro + fn * 16 + lrow) * 128 + ks * 64 + lk * 16)) ^ aswz;
        bfr[fn][ks] = *(const short8*)(Bb + ph);
      }

#pragma unroll
    for (int p = 0; p < 4; p++) {
      short8 af[2][2];
#pragma unroll
      for (int rr = 0; rr < 2; rr++)
#pragma unroll
        for (int ks = 0; ks < 2; ks++) {
          const int ph =
              ((((p * 2 + rr) * 16 + lrow) * 128 + ks * 64 + lk * 16)) ^ aswz;
          af[rr][ks] = *(const short8*)(Ab + ph);
        }
      if (p == 0) {
        if (kt + 1 < NT) STAGE_B((kt + 1) & 1, (size_t)(kt + 1) * 64);
        if (kt + 2 < NT) STAGE_A((kt + 2) % 3, (size_t)(kt + 2) * 64);
      }
      __builtin_amdgcn_s_barrier();
      __builtin_amdgcn_sched_barrier(0);
      __builtin_amdgcn_s_setprio(1);
#pragma unroll
      for (int ks = 0; ks < 2; ks++)
#pragma unroll
        for (int rr = 0; rr < 2; rr++)
#pragma unroll
          for (int fn = 0; fn < 4; fn++)
            acc[p * 2 + rr][fn] = __builtin_amdgcn_mfma_f32_16x16x32_bf16(
                af[rr][ks], bfr[fn][ks], acc[p * 2 + rr][fn], 0, 0, 0);
      __builtin_amdgcn_s_setprio(0);
      __builtin_amdgcn_s_barrier();
      __builtin_amdgcn_sched_barrier(0);
    }
    if (kt + 1 < NT) {
      if (kt + 2 < NT)
        asm volatile("s_waitcnt vmcnt(4)" ::: "memory");
      else
        asm volatile("s_waitcnt vmcnt(0)" ::: "memory");
      __builtin_amdgcn_s_barrier();
      __builtin_amdgcn_sched_barrier(0);
    }
  }
#undef STAGE_A
#undef STAGE_B

#pragma unroll
  for (int fn = 0; fn < 4; fn++) {
    const size_t col = n0 + wn * 64 + fn * 16 + lrow;
    const float bv_ = bias ? bias[col] : 0.f;
#pragma unroll
    for (int fr = 0; fr < 8; fr++) {
#pragma unroll
      for (int q = 0; q < 4; q++) {
        const size_t row = m0 + wm * 128 + fr * 16 + lk * 4 + q;
        const float v = acc[fr][fn][q] + bv_;
        if (OUT_BF16)
          ((short*)Cv)[row * ldc + col] = f2b(v);
        else
          ((float*)Cv)[row * ldc + col] = v;
      }
    }
  }
}

// ---------- fused scores + softmax + AH, one block per position t ----------
// histT: [d][slot][8] bf16 where slot = (h>>3) ^ ((d>>1)&3)  (16B-slot swizzle).
__global__ __launch_bounds__(512) void k_fused(const short* __restrict__ xA,
                                               const float* __restrict__ hist,
                                               const float* __restrict__ u3,
                                               const float* __restrict__ decay,
                                               short* __restrict__ CC) {
  extern __shared__ char smem[];
  short* histT = (short*)smem;                         // [1024][32] bf16, 64KB
  float* spart = (float*)(smem + 65536);               // [4][16][32] f32, 8KB
  float* sfull = (float*)(smem + 65536 + 8192);        // [16][32] f32, 2KB
  short* attnb = (short*)(smem + 65536 + 8192 + 2048); // [16][32] bf16, 1KB

  const int t = blockIdx.x;
  const int tid = threadIdx.x;
  const int w = tid >> 6, l = tid & 63;
  const int lrow = l & 15, lk = l >> 4;

  f32x4 accs[2];
  accs[0] = (f32x4){0.f, 0.f, 0.f, 0.f};
  accs[1] = (f32x4){0.f, 0.f, 0.f, 0.f};

#pragma unroll
  for (int kk = 0; kk < 4; kk++) {
    const int ka = (w * 4 + kk) * 32 + lk * 8;
    short8 af;
    if (lrow < 8) {
      af = *(const short8*)(xA + ((size_t)lrow * TT + t) * DD + ka);
    } else if (lrow == 8) {
      const float* up = u3 + ka;
#pragma unroll
      for (int j = 0; j < 8; j++) af[j] = f2b(up[j]);
    } else {
#pragma unroll
      for (int j = 0; j < 8; j++) af[j] = 0;
    }
#pragma unroll
    for (int nt = 0; nt < 2; nt++) {
      const int h = lrow + nt * 16;
      const float* hp = hist + ((size_t)t * HH + h) * DD + ka;
      float4 h0 = *(const float4*)hp;
      float4 h1 = *(const float4*)(hp + 4);
      short8 bv_;
      bv_[0] = f2b(h0.x); bv_[1] = f2b(h0.y); bv_[2] = f2b(h0.z); bv_[3] = f2b(h0.w);
      bv_[4] = f2b(h1.x); bv_[5] = f2b(h1.y); bv_[6] = f2b(h1.z); bv_[7] = f2b(h1.w);
      accs[nt] = __builtin_amdgcn_mfma_f32_16x16x32_bf16(af, bv_, accs[nt], 0, 0, 0);
      const int hs = h >> 3, hl = h & 7;
#pragma unroll
      for (int j = 0; j < 8; j++) {
        const int d = ka + j;
        histT[(d << 5) + ((hs ^ ((d >> 1) & 3)) << 3) + hl] = bv_[j];
      }
    }
  }

  // deterministic cross-wave score reduction (8 -> 1)
  for (int half = 4; half >= 1; half >>= 1) {
    __syncthreads();
    if (w >= half && w < 2 * half) {
#pragma unroll
      for (int nt = 0; nt < 2; nt++)
#pragma unroll
        for (int q = 0; q < 4; q++)
          spart[(w - half) * 512 + (lk * 4 + q) * 32 + nt * 16 + lrow] = accs[nt][q];
    }
    __syncthreads();
    if (w < half) {
#pragma unroll
      for (int nt = 0; nt < 2; nt++)
#pragma unroll
        for (int q = 0; q < 4; q++)
          accs[nt][q] += spart[w * 512 + (lk * 4 + q) * 32 + nt * 16 + lrow];
    }
  }
  if (w == 0) {
#pragma unroll
    for (int nt = 0; nt < 2; nt++)
#pragma unroll
      for (int q = 0; q < 4; q++)
        sfull[(lk * 4 + q) * 32 + nt * 16 + lrow] = accs[nt][q];
  }
  __syncthreads();

  // softmax over h within 32-thread groups (b = tid>>5)
  {
    const int bb = tid >> 5, h = tid & 31;
    float s = (sfull[bb * 32 + h] + sfull[8 * 32 + h]) * (1.0f / 32.0f) +
              logf(decay[31 - h] + 1e-10f);
    float m = s;
#pragma unroll
    for (int msk = 16; msk >= 1; msk >>= 1) m = fmaxf(m, __shfl_xor(m, msk));
    float p = expf(s - m);
    float den = p;
#pragma unroll
    for (int msk = 16; msk >= 1; msk >>= 1) den += __shfl_xor(den, msk);
    attnb[bb * 32 + h] = f2b(p / den);
  }
  __syncthreads();

  // phase 3: AH[b,d] = sum_h attn[b,h]*hist[h,d]; wave w covers d in [w*128,(w+1)*128)
  short8 paf = *(const short8*)(attnb + lrow * 32 + lk * 8);
  const f32x4 z4 = (f32x4){0.f, 0.f, 0.f, 0.f};
#pragma unroll
  for (int i = 0; i < 8; i++) {
    const int d0 = (w * 8 + i) * 16;
    const int d = d0 + lrow;
    short8 hb = *(const short8*)(histT + (d << 5) + ((lk ^ ((d >> 1) & 3)) << 3));
    f32x4 o = __builtin_amdgcn_mfma_f32_16x16x32_bf16(paf, hb, z4, 0, 0, 0);
    if (lk < 2) {
#pragma unroll
      for (int q = 0; q < 4; q++) {
        const int b = lk * 4 + q;
        CC[((size_t)b * TT + t) * 2048 + d0 + lrow] = f2b(o[q]);
      }
    }
  }
}

extern "C" void kernel_launch(void* const* d_in, const int* in_sizes, int n_in,
                              void* d_out, int out_size, void* d_ws, size_t ws_size,
                              hipStream_t stream) {
  (void)in_sizes; (void)n_in; (void)out_size; (void)ws_size;
  const float* x    = (const float*)d_in[0];
  const float* hist = (const float*)d_in[1];
  const float* Wq   = (const float*)d_in[2];
  const float* bq   = (const float*)d_in[3];
  const float* Wk   = (const float*)d_in[4];
  // d_in[5] = bk: h-constant in scores -> softmax-invariant, dropped exactly.
  const float* Wv   = (const float*)d_in[6];
  const float* bv   = (const float*)d_in[7];
  const float* Wo   = (const float*)d_in[8];
  const float* bo   = (const float*)d_in[9];
  const float* dec  = (const float*)d_in[10];
  float* out = (float*)d_out;
  char* ws = (char*)d_ws;

  short* CC   = (short*)(ws + 0);          // [16384][2048] bf16: [AH | x]
  short* xA   = (short*)(ws + 67108864);   // [16384][1024] bf16
  short* A2   = (short*)(ws + 100663296);  // [1024][1024] bf16 = Wk^T Wq
  short* WB   = (short*)(ws + 102760448);  // [1024][2048] bf16: [Wvo | Wo]
  short* WqT  = (short*)(ws + 106954752);
  short* WkT  = (short*)(ws + 109051904);
  short* WvT  = (short*)(ws + 111149056);
  float* bfin = (float*)(ws + 113246208);
  float* u3   = (float*)(ws + 113250304);

  hipFuncSetAttribute((const void*)k_fused, hipFuncAttributeMaxDynamicSharedMemorySize,
                      76800);
  hipFuncSetAttribute((const void*)k_gemm256<true>,
                      hipFuncAttributeMaxDynamicSharedMemorySize, 163840);
  hipFuncSetAttribute((const void*)k_gemm256<false>,
                      hipFuncAttributeMaxDynamicSharedMemorySize, 163840);

  // all prep in one launch
  k_prep<<<12804, 256, 0, stream>>>(x, Wq, bq, Wk, Wv, bv, Wo, bo, WqT, WkT, WvT, CC,
                                    WB, u3, bfin);
  // A2 = Wk^T Wq  and  Wvo = Wo*Wv (into WB left half), batched
  k_gemm64x2<<<dim3(16, 16, 2), 256, 0, stream>>>(WkT, WqT, A2, WB + 1024, WvT, WB);
  // xA = x_bf16 * A2^T   (M=16384, N=1024, K=1024 -> 256 blocks, 4 n-blocks)
  k_gemm256<true><<<256, 512, 163840, stream>>>(CC + 1024, 2048, A2, 1024, xA, 1024,
                                                1024, nullptr, 4);
  // fused scores/softmax/AH -> CC left half
  k_fused<<<2048, 512, 76800, stream>>>(xA, hist, u3, dec, CC);
  // out = [AH|x] * [Wvo|Wo]^T + bfinal   (M=16384, N=1024, K=2048 -> 256 blocks)
  k_gemm256<false><<<256, 512, 163840, stream>>>(CC, 2048, WB, 2048, out, 1024, 2048,
                                                 bfin, 4);
}

// Round 7
// 268.254 us; speedup vs baseline: 1.0770x; 1.0770x over previous
//
#include <hip/hip_runtime.h>

// HistoryAttention, restructured:
//   A2  = Wk^T Wq                  (so xA = x@(Wq^T Wk) = x · A2^T)
//   xA  = x_bf16 · A2^T            [16384,1024]
//   scores[b,t,h] = (xA[b,t]·hist[t,h] + hist[t,h]·u3)/32 + log(decay[31-h]+1e-10)
//   AH[b,t] = sum_h softmax(scores)·hist[t,h]
//   out = [AH | x] · [Wvo | Wo]^T + (Wo·bv + bo),  Wvo = Wo·Wv
// Big GEMMs: 256x256/BK=64, A 3-ring + B 2-ring, ONE barrier per K-tile
// (counted vmcnt(4)); no per-phase barriers -> compiler pipelines ds_read/MFMA.

#define BB 8
#define TT 2048
#define DD 1024
#define HH 32

typedef __attribute__((ext_vector_type(8))) short short8;
typedef __attribute__((ext_vector_type(4))) float f32x4;

__device__ __forceinline__ short f2b(float f) {
  unsigned u = __float_as_uint(f);
  unsigned r = u + 0x7fffu + ((u >> 16) & 1u);
  return (short)(r >> 16);
}

__device__ __forceinline__ void gload_lds16(const void* g, void* l) {
  __builtin_amdgcn_global_load_lds(
      (const __attribute__((address_space(1))) void*)g,
      (__attribute__((address_space(3))) void*)l, 16, 0, 0);
}

// ---------- fused prep: weight transposes, bf16 converts, u3, bfinal ----------
__global__ __launch_bounds__(256) void k_prep(
    const float* __restrict__ x, const float* __restrict__ Wq,
    const float* __restrict__ bq, const float* __restrict__ Wk,
    const float* __restrict__ Wv, const float* __restrict__ bv,
    const float* __restrict__ Wo, const float* __restrict__ bo,
    short* __restrict__ WqT, short* __restrict__ WkT, short* __restrict__ WvT,
    short* __restrict__ CC, short* __restrict__ WB, float* __restrict__ u3,
    float* __restrict__ bfin) {
  const int b = blockIdx.x;
  const int tid = threadIdx.x;
  if (b < 3072) {
    __shared__ float tile[32][33];
    const int z = b >> 10, rem = b & 1023;
    const float* src = z == 0 ? Wq : (z == 1 ? Wk : Wv);
    short* dst = z == 0 ? WqT : (z == 1 ? WkT : WvT);
    const int bx = (rem & 31) * 32, by = (rem >> 5) * 32;
    const int tx = tid & 31, ty = tid >> 5;
#pragma unroll
    for (int k = 0; k < 4; k++)
      tile[ty + 8 * k][tx] = src[(size_t)(by + ty + 8 * k) * DD + bx + tx];
    __syncthreads();
#pragma unroll
    for (int k = 0; k < 4; k++)
      dst[(size_t)(bx + ty + 8 * k) * DD + by + tx] = f2b(tile[tx][ty + 8 * k]);
  } else if (b < 11776) {
    const bool isx = b < 11264;
    const float* src = isx ? x : Wo;
    short* dst = isx ? CC : WB;
    size_t i = (((size_t)(b - (isx ? 3072 : 11264))) * 256 + tid) * 8;
    float4 a = *(const float4*)(src + i);
    float4 c = *(const float4*)(src + i + 4);
    short8 o;
    o[0] = f2b(a.x); o[1] = f2b(a.y); o[2] = f2b(a.z); o[3] = f2b(a.w);
    o[4] = f2b(c.x); o[5] = f2b(c.y); o[6] = f2b(c.z); o[7] = f2b(c.w);
    size_t r = i >> 10, cc = i & 1023;
    *(short8*)(dst + r * 2048 + 1024 + cc) = o;
  } else if (b < 11780) {
    const int d = (b - 11776) * 256 + tid;
    float a0 = 0, a1 = 0, a2 = 0, a3 = 0;
    for (int j = 0; j < DD; j += 4) {
      a0 = fmaf(Wk[(size_t)(j + 0) * DD + d], bq[j + 0], a0);
      a1 = fmaf(Wk[(size_t)(j + 1) * DD + d], bq[j + 1], a1);
      a2 = fmaf(Wk[(size_t)(j + 2) * DD + d], bq[j + 2], a2);
      a3 = fmaf(Wk[(size_t)(j + 3) * DD + d], bq[j + 3], a3);
    }
    u3[d] = (a0 + a1) + (a2 + a3);
  } else {
    const int j = b - 11780;
    float acc = 0.f;
    for (int d = tid; d < DD; d += 256) acc = fmaf(Wo[(size_t)j * DD + d], bv[d], acc);
#pragma unroll
    for (int off = 32; off >= 1; off >>= 1) acc += __shfl_down(acc, off);
    __shared__ float p[4];
    if ((tid & 63) == 0) p[tid >> 6] = acc;
    __syncthreads();
    if (tid == 0) bfin[j] = p[0] + p[1] + p[2] + p[3] + bo[j];
  }
}

// ---------- batched 64x64-tile GEMM for the two 1024^3 weight products ----------
__global__ __launch_bounds__(256) void k_gemm64x2(const short* __restrict__ WkT,
                                                  const short* __restrict__ WqT,
                                                  short* __restrict__ A2,
                                                  const short* __restrict__ WoB,
                                                  const short* __restrict__ WvT,
                                                  short* __restrict__ WB) {
  __shared__ short At[64 * 32];
  __shared__ short Bt[64 * 32];
  const short* A; const short* B; short* C; int lda, ldb, ldc;
  if (blockIdx.z == 0) {
    A = WkT; lda = 1024; B = WqT; ldb = 1024; C = A2; ldc = 1024;
  } else {
    A = WoB; lda = 2048; B = WvT; ldb = 1024; C = WB; ldc = 2048;
  }
  const int tid = threadIdx.x;
  const int w = tid >> 6, l = tid & 63;
  const int wm = w >> 1, wn = w & 1;
  const int lrow = l & 15, lk = l >> 4;
  const size_t m0 = (size_t)blockIdx.x * 64;
  const size_t n0 = (size_t)blockIdx.y * 64;

  f32x4 acc[2][2];
#pragma unroll
  for (int i = 0; i < 2; i++)
#pragma unroll
    for (int j = 0; j < 2; j++) acc[i][j] = (f32x4){0.f, 0.f, 0.f, 0.f};

  const unsigned ubase = (unsigned)((tid & ~63) * 16);
  const int r0 = tid >> 2, kc = tid & 3;

  for (int k0 = 0; k0 < 1024; k0 += 32) {
    __syncthreads();
    gload_lds16(A + (m0 + r0) * lda + k0 + kc * 8, (char*)At + ubase);
    gload_lds16(B + (n0 + r0) * ldb + k0 + kc * 8, (char*)Bt + ubase);
    __syncthreads();
    short8 af[2], bfv[2];
    const int aoff = (wm * 32 + lrow) * 32 + lk * 8;
    const int boff = (wn * 32 + lrow) * 32 + lk * 8;
#pragma unroll
    for (int mi = 0; mi < 2; mi++) af[mi] = *(const short8*)(At + aoff + mi * 512);
#pragma unroll
    for (int ni = 0; ni < 2; ni++) bfv[ni] = *(const short8*)(Bt + boff + ni * 512);
#pragma unroll
    for (int mi = 0; mi < 2; mi++)
#pragma unroll
      for (int ni = 0; ni < 2; ni++)
        acc[mi][ni] = __builtin_amdgcn_mfma_f32_16x16x32_bf16(af[mi], bfv[ni],
                                                              acc[mi][ni], 0, 0, 0);
  }

#pragma unroll
  for (int ni = 0; ni < 2; ni++) {
    const size_t col = n0 + wn * 32 + ni * 16 + lrow;
#pragma unroll
    for (int mi = 0; mi < 2; mi++) {
#pragma unroll
      for (int q = 0; q < 4; q++) {
        const size_t row = m0 + wm * 32 + mi * 16 + lk * 4 + q;
        C[row * ldc + col] = f2b(acc[mi][ni][q]);
      }
    }
  }
}

// ---------- 256x256 / BK=64, 8 waves, st_16x32 swizzle, 1 barrier per K-tile ----
// LDS 160KB: A ring 3x32KB at 0 (2-tile prefetch), B ring 2x32KB at +96KB.
// Stage at tile top: B(t+1), A(t+2). Boundary: vmcnt(4) (A(t+2) may stay in
// flight; in-order vmcnt => A(t+1),B(t+1) drained) + one s_barrier. No
// per-phase barriers: slots being staged are never the slots being read in
// tiles t..t+1, so compiler freely pipelines ds_read with MFMA inside a tile.
template <bool OUT_BF16>
__global__ __launch_bounds__(512) void k_gemm256(const short* __restrict__ A, int lda,
                                                 const short* __restrict__ B, int ldb,
                                                 void* __restrict__ Cv, int ldc, int K,
                                                 const float* __restrict__ bias,
                                                 int nblocks) {
  extern __shared__ char lds[];
  char* ldsA = lds;            // 3 x 32KB
  char* ldsB = lds + 98304;    // 2 x 32KB
  const int tid = threadIdx.x;
  const int w = tid >> 6;
  const int l = tid & 63;
  const int wm = w >> 2, wn = w & 3;
  const int lrow = l & 15, lk = l >> 4;

  // XCD-aware swizzle (gridDim.x % 8 == 0); nb fast within each XCD's chunk
  const int nwg = gridDim.x;
  const int cpx = nwg >> 3;
  const int lin = blockIdx.x;
  const int wg = (lin & 7) * cpx + (lin >> 3);
  const int mb = wg / nblocks;
  const int nb = wg % nblocks;
  const size_t m0 = (size_t)mb * 256;
  const size_t n0 = (size_t)nb * 256;

  // staging decode: physical q = tid*16 -> logical = q ^ ((q>>9&1)<<5)
  const int r0 = tid >> 3;
  const int r1 = 64 + (tid >> 3);
  const int kk0 = (((tid & 7) * 16) ^ (((tid >> 5) & 1) << 5)) >> 1;
  const short* pA00 = A + (m0 + r0) * lda + kk0;
  const short* pA01 = A + (m0 + r1) * lda + kk0;
  const short* pA10 = A + (m0 + 128 + r0) * lda + kk0;
  const short* pA11 = A + (m0 + 128 + r1) * lda + kk0;
  const short* pB00 = B + (n0 + r0) * ldb + kk0;
  const short* pB01 = B + (n0 + r1) * ldb + kk0;
  const short* pB10 = B + (n0 + 128 + r0) * ldb + kk0;
  const short* pB11 = B + (n0 + 128 + r1) * ldb + kk0;
  const unsigned wb16 = (unsigned)((tid & ~63) * 16);

  f32x4 acc[8][4];
#pragma unroll
  for (int i = 0; i < 8; i++)
#pragma unroll
    for (int j = 0; j < 4; j++) acc[i][j] = (f32x4){0.f, 0.f, 0.f, 0.f};

  const int NT = K >> 6;

#define STAGE_A(bufsel, koff)                                     \
  do {                                                            \
    char* ab_ = ldsA + (bufsel) * 32768;                          \
    gload_lds16(pA00 + (koff), ab_ + wb16);                       \
    gload_lds16(pA01 + (koff), ab_ + 8192 + wb16);                \
    gload_lds16(pA10 + (koff), ab_ + 16384 + wb16);               \
    gload_lds16(pA11 + (koff), ab_ + 24576 + wb16);               \
  } while (0)
#define STAGE_B(bufsel, koff)                                     \
  do {                                                            \
    char* bb_ = ldsB + (bufsel) * 32768;                          \
    gload_lds16(pB00 + (koff), bb_ + wb16);                       \
    gload_lds16(pB01 + (koff), bb_ + 8192 + wb16);                \
    gload_lds16(pB10 + (koff), bb_ + 16384 + wb16);               \
    gload_lds16(pB11 + (koff), bb_ + 24576 + wb16);               \
  } while (0)

  // prologue: B0, A0, A1 in flight; wait for B0,A0 (allow A1 outstanding)
  STAGE_B(0, 0);
  STAGE_A(0, 0);
  if (NT > 1) {
    STAGE_A(1, 64);
    asm volatile("s_waitcnt vmcnt(4)" ::: "memory");
  } else {
    asm volatile("s_waitcnt vmcnt(0)" ::: "memory");
  }
  __builtin_amdgcn_s_barrier();
  __builtin_amdgcn_sched_barrier(0);

  const int aswz = ((lrow >> 2) & 1) << 5;  // st_16x32: flip bit5 when row bit2 set

  for (int kt = 0; kt < NT; ++kt) {
    const char* Ab = ldsA + (kt % 3) * 32768 + wm * 16384;
    const char* Bb = ldsB + (kt & 1) * 32768 + (wn >> 1) * 16384;
    const int bro = (wn & 1) * 64;

    // issue next-tile staging first; it completes under this tile's compute
    if (kt + 1 < NT) STAGE_B((kt + 1) & 1, (size_t)(kt + 1) * 64);
    if (kt + 2 < NT) STAGE_A((kt + 2) % 3, (size_t)(kt + 2) * 64);

    short8 bfr[4][2];
#pragma unroll
    for (int fn = 0; fn < 4; fn++)
#pragma unroll
      for (int ks = 0; ks < 2; ks++) {
        const int ph = (((bro + fn * 16 + lrow) * 128 + ks * 64 + lk * 16)) ^ aswz;
        bfr[fn][ks] = *(const short8*)(Bb + ph);
      }

#pragma unroll
    for (int p = 0; p < 4; p++) {
      short8 af[2][2];
#pragma unroll
      for (int rr = 0; rr < 2; rr++)
#pragma unroll
        for (int ks = 0; ks < 2; ks++) {
          const int ph =
              ((((p * 2 + rr) * 16 + lrow) * 128 + ks * 64 + lk * 16)) ^ aswz;
          af[rr][ks] = *(const short8*)(Ab + ph);
        }
#pragma unroll
      for (int ks = 0; ks < 2; ks++)
#pragma unroll
        for (int rr = 0; rr < 2; rr++)
#pragma unroll
          for (int fn = 0; fn < 4; fn++)
            acc[p * 2 + rr][fn] = __builtin_amdgcn_mfma_f32_16x16x32_bf16(
                af[rr][ks], bfr[fn][ks], acc[p * 2 + rr][fn], 0, 0, 0);
    }

    if (kt + 1 < NT) {
      if (kt + 2 < NT)
        asm volatile("s_waitcnt vmcnt(4)" ::: "memory");
      else
        asm volatile("s_waitcnt vmcnt(0)" ::: "memory");
      __builtin_amdgcn_s_barrier();
      __builtin_amdgcn_sched_barrier(0);
    }
  }
#undef STAGE_A
#undef STAGE_B

#pragma unroll
  for (int fn = 0; fn < 4; fn++) {
    const size_t col = n0 + wn * 64 + fn * 16 + lrow;
    const float bv_ = bias ? bias[col] : 0.f;
#pragma unroll
    for (int fr = 0; fr < 8; fr++) {
#pragma unroll
      for (int q = 0; q < 4; q++) {
        const size_t row = m0 + wm * 128 + fr * 16 + lk * 4 + q;
        const float v = acc[fr][fn][q] + bv_;
        if (OUT_BF16)
          ((short*)Cv)[row * ldc + col] = f2b(v);
        else
          ((float*)Cv)[row * ldc + col] = v;
      }
    }
  }
}

// ---------- fused scores + softmax + AH, one block per position t ----------
// histT: [d][slot][8] bf16 where slot = (h>>3) ^ ((d>>1)&3)  (16B-slot swizzle).
__global__ __launch_bounds__(512) void k_fused(const short* __restrict__ xA,
                                               const float* __restrict__ hist,
                                               const float* __restrict__ u3,
                                               const float* __restrict__ decay,
                                               short* __restrict__ CC) {
  extern __shared__ char smem[];
  short* histT = (short*)smem;                         // [1024][32] bf16, 64KB
  float* spart = (float*)(smem + 65536);               // [4][16][32] f32, 8KB
  float* sfull = (float*)(smem + 65536 + 8192);        // [16][32] f32, 2KB
  short* attnb = (short*)(smem + 65536 + 8192 + 2048); // [16][32] bf16, 1KB

  const int t = blockIdx.x;
  const int tid = threadIdx.x;
  const int w = tid >> 6, l = tid & 63;
  const int lrow = l & 15, lk = l >> 4;

  f32x4 accs[2];
  accs[0] = (f32x4){0.f, 0.f, 0.f, 0.f};
  accs[1] = (f32x4){0.f, 0.f, 0.f, 0.f};

#pragma unroll
  for (int kk = 0; kk < 4; kk++) {
    const int ka = (w * 4 + kk) * 32 + lk * 8;
    short8 af;
    if (lrow < 8) {
      af = *(const short8*)(xA + ((size_t)lrow * TT + t) * DD + ka);
    } else if (lrow == 8) {
      const float* up = u3 + ka;
#pragma unroll
      for (int j = 0; j < 8; j++) af[j] = f2b(up[j]);
    } else {
#pragma unroll
      for (int j = 0; j < 8; j++) af[j] = 0;
    }
#pragma unroll
    for (int nt = 0; nt < 2; nt++) {
      const int h = lrow + nt * 16;
      const float* hp = hist + ((size_t)t * HH + h) * DD + ka;
      float4 h0 = *(const float4*)hp;
      float4 h1 = *(const float4*)(hp + 4);
      short8 bv_;
      bv_[0] = f2b(h0.x); bv_[1] = f2b(h0.y); bv_[2] = f2b(h0.z); bv_[3] = f2b(h0.w);
      bv_[4] = f2b(h1.x); bv_[5] = f2b(h1.y); bv_[6] = f2b(h1.z); bv_[7] = f2b(h1.w);
      accs[nt] = __builtin_amdgcn_mfma_f32_16x16x32_bf16(af, bv_, accs[nt], 0, 0, 0);
      const int hs = h >> 3, hl = h & 7;
#pragma unroll
      for (int j = 0; j < 8; j++) {
        const int d = ka + j;
        histT[(d << 5) + ((hs ^ ((d >> 1) & 3)) << 3) + hl] = bv_[j];
      }
    }
  }

  // deterministic cross-wave score reduction (8 -> 1)
  for (int half = 4; half >= 1; half >>= 1) {
    __syncthreads();
    if (w >= half && w < 2 * half) {
#pragma unroll
      for (int nt = 0; nt < 2; nt++)
#pragma unroll
        for (int q = 0; q < 4; q++)
          spart[(w - half) * 512 + (lk * 4 + q) * 32 + nt * 16 + lrow] = accs[nt][q];
    }
    __syncthreads();
    if (w < half) {
#pragma unroll
      for (int nt = 0; nt < 2; nt++)
#pragma unroll
        for (int q = 0; q < 4; q++)
          accs[nt][q] += spart[w * 512 + (lk * 4 + q) * 32 + nt * 16 + lrow];
    }
  }
  if (w == 0) {
#pragma unroll
    for (int nt = 0; nt < 2; nt++)
#pragma unroll
      for (int q = 0; q < 4; q++)
        sfull[(lk * 4 + q) * 32 + nt * 16 + lrow] = accs[nt][q];
  }
  __syncthreads();

  // softmax over h within 32-thread groups (b = tid>>5)
  {
    const int bb = tid >> 5, h = tid & 31;
    float s = (sfull[bb * 32 + h] + sfull[8 * 32 + h]) * (1.0f / 32.0f) +
              logf(decay[31 - h] + 1e-10f);
    float m = s;
#pragma unroll
    for (int msk = 16; msk >= 1; msk >>= 1) m = fmaxf(m, __shfl_xor(m, msk));
    float p = expf(s - m);
    float den = p;
#pragma unroll
    for (int msk = 16; msk >= 1; msk >>= 1) den += __shfl_xor(den, msk);
    attnb[bb * 32 + h] = f2b(p / den);
  }
  __syncthreads();

  // phase 3: AH[b,d] = sum_h attn[b,h]*hist[h,d]; wave w covers d in [w*128,(w+1)*128)
  short8 paf = *(const short8*)(attnb + lrow * 32 + lk * 8);
  const f32x4 z4 = (f32x4){0.f, 0.f, 0.f, 0.f};
#pragma unroll
  for (int i = 0; i < 8; i++) {
    const int d0 = (w * 8 + i) * 16;
    const int d = d0 + lrow;
    short8 hb = *(const short8*)(histT + (d << 5) + ((lk ^ ((d >> 1) & 3)) << 3));
    f32x4 o = __builtin_amdgcn_mfma_f32_16x16x32_bf16(paf, hb, z4, 0, 0, 0);
    if (lk < 2) {
#pragma unroll
      for (int q = 0; q < 4; q++) {
        const int b = lk * 4 + q;
        CC[((size_t)b * TT + t) * 2048 + d0 + lrow] = f2b(o[q]);
      }
    }
  }
}

extern "C" void kernel_launch(void* const* d_in, const int* in_sizes, int n_in,
                              void* d_out, int out_size, void* d_ws, size_t ws_size,
                              hipStream_t stream) {
  (void)in_sizes; (void)n_in; (void)out_size; (void)ws_size;
  const float* x    = (const float*)d_in[0];
  const float* hist = (const float*)d_in[1];
  const float* Wq   = (const float*)d_in[2];
  const float* bq   = (const float*)d_in[3];
  const float* Wk   = (const float*)d_in[4];
  // d_in[5] = bk: h-constant in scores -> softmax-invariant, dropped exactly.
  const float* Wv   = (const float*)d_in[6];
  const float* bv   = (const float*)d_in[7];
  const float* Wo   = (const float*)d_in[8];
  const float* bo   = (const float*)d_in[9];
  const float* dec  = (const float*)d_in[10];
  float* out = (float*)d_out;
  char* ws = (char*)d_ws;

  short* CC   = (short*)(ws + 0);          // [16384][2048] bf16: [AH | x]
  short* xA   = (short*)(ws + 67108864);   // [16384][1024] bf16
  short* A2   = (short*)(ws + 100663296);  // [1024][1024] bf16 = Wk^T Wq
  short* WB   = (short*)(ws + 102760448);  // [1024][2048] bf16: [Wvo | Wo]
  short* WqT  = (short*)(ws + 106954752);
  short* WkT  = (short*)(ws + 109051904);
  short* WvT  = (short*)(ws + 111149056);
  float* bfin = (float*)(ws + 113246208);
  float* u3   = (float*)(ws + 113250304);

  hipFuncSetAttribute((const void*)k_fused, hipFuncAttributeMaxDynamicSharedMemorySize,
                      76800);
  hipFuncSetAttribute((const void*)k_gemm256<true>,
                      hipFuncAttributeMaxDynamicSharedMemorySize, 163840);
  hipFuncSetAttribute((const void*)k_gemm256<false>,
                      hipFuncAttributeMaxDynamicSharedMemorySize, 163840);

  // all prep in one launch
  k_prep<<<12804, 256, 0, stream>>>(x, Wq, bq, Wk, Wv, bv, Wo, bo, WqT, WkT, WvT, CC,
                                    WB, u3, bfin);
  // A2 = Wk^T Wq  and  Wvo = Wo*Wv (into WB left half), batched
  k_gemm64x2<<<dim3(16, 16, 2), 256, 0, stream>>>(WkT, WqT, A2, WB + 1024, WvT, WB);
  // xA = x_bf16 * A2^T   (M=16384, N=1024, K=1024 -> 256 blocks, 4 n-blocks)
  k_gemm256<true><<<256, 512, 163840, stream>>>(CC + 1024, 2048, A2, 1024, xA, 1024,
                                                1024, nullptr, 4);
  // fused scores/softmax/AH -> CC left half
  k_fused<<<2048, 512, 76800, stream>>>(xA, hist, u3, dec, CC);
  // out = [AH|x] * [Wvo|Wo]^T + bfinal   (M=16384, N=1024, K=2048 -> 256 blocks)
  k_gemm256<false><<<256, 512, 163840, stream>>>(CC, 2048, WB, 2048, out, 1024, 2048,
                                                 bfin, 4);
}

// Round 8
// 266.169 us; speedup vs baseline: 1.0854x; 1.0078x over previous
//
#include <hip/hip_runtime.h>

// HistoryAttention, restructured:
//   A2  = Wk^T Wq                  (so xA = x@(Wq^T Wk) = x · A2^T)
//   xA  = x_bf16 · A2^T            [16384,1024]
//   scores[b,t,h] = (xA[b,t]·hist[t,h] + hist[t,h]·u3)/32 + log(decay[31-h]+1e-10)
//   AH[b,t] = sum_h softmax(scores)·hist[t,h]
//   out = [AH | x] · [Wvo | Wo]^T + (Wo·bv + bo),  Wvo = Wo·Wv
// Big GEMMs: 128x128/BK=64, 4 waves, A 3-ring + B 2-ring (80KB -> 2 blocks/CU),
// one counted-vmcnt barrier per K-tile; cross-block overlap hides the boundary.

#define BB 8
#define TT 2048
#define DD 1024
#define HH 32

typedef __attribute__((ext_vector_type(8))) short short8;
typedef __attribute__((ext_vector_type(4))) float f32x4;

__device__ __forceinline__ short f2b(float f) {
  unsigned u = __float_as_uint(f);
  unsigned r = u + 0x7fffu + ((u >> 16) & 1u);
  return (short)(r >> 16);
}

__device__ __forceinline__ void gload_lds16(const void* g, void* l) {
  __builtin_amdgcn_global_load_lds(
      (const __attribute__((address_space(1))) void*)g,
      (__attribute__((address_space(3))) void*)l, 16, 0, 0);
}

// ---------- fused prep: weight transposes, bf16 converts, u3, bfinal ----------
__global__ __launch_bounds__(256) void k_prep(
    const float* __restrict__ x, const float* __restrict__ Wq,
    const float* __restrict__ bq, const float* __restrict__ Wk,
    const float* __restrict__ Wv, const float* __restrict__ bv,
    const float* __restrict__ Wo, const float* __restrict__ bo,
    short* __restrict__ WqT, short* __restrict__ WkT, short* __restrict__ WvT,
    short* __restrict__ CC, short* __restrict__ WB, float* __restrict__ u3,
    float* __restrict__ bfin) {
  const int b = blockIdx.x;
  const int tid = threadIdx.x;
  if (b < 3072) {
    __shared__ float tile[32][33];
    const int z = b >> 10, rem = b & 1023;
    const float* src = z == 0 ? Wq : (z == 1 ? Wk : Wv);
    short* dst = z == 0 ? WqT : (z == 1 ? WkT : WvT);
    const int bx = (rem & 31) * 32, by = (rem >> 5) * 32;
    const int tx = tid & 31, ty = tid >> 5;
#pragma unroll
    for (int k = 0; k < 4; k++)
      tile[ty + 8 * k][tx] = src[(size_t)(by + ty + 8 * k) * DD + bx + tx];
    __syncthreads();
#pragma unroll
    for (int k = 0; k < 4; k++)
      dst[(size_t)(bx + ty + 8 * k) * DD + by + tx] = f2b(tile[tx][ty + 8 * k]);
  } else if (b < 11776) {
    const bool isx = b < 11264;
    const float* src = isx ? x : Wo;
    short* dst = isx ? CC : WB;
    size_t i = (((size_t)(b - (isx ? 3072 : 11264))) * 256 + tid) * 8;
    float4 a = *(const float4*)(src + i);
    float4 c = *(const float4*)(src + i + 4);
    short8 o;
    o[0] = f2b(a.x); o[1] = f2b(a.y); o[2] = f2b(a.z); o[3] = f2b(a.w);
    o[4] = f2b(c.x); o[5] = f2b(c.y); o[6] = f2b(c.z); o[7] = f2b(c.w);
    size_t r = i >> 10, cc = i & 1023;
    *(short8*)(dst + r * 2048 + 1024 + cc) = o;
  } else if (b < 11780) {
    const int d = (b - 11776) * 256 + tid;
    float a0 = 0, a1 = 0, a2 = 0, a3 = 0;
    for (int j = 0; j < DD; j += 4) {
      a0 = fmaf(Wk[(size_t)(j + 0) * DD + d], bq[j + 0], a0);
      a1 = fmaf(Wk[(size_t)(j + 1) * DD + d], bq[j + 1], a1);
      a2 = fmaf(Wk[(size_t)(j + 2) * DD + d], bq[j + 2], a2);
      a3 = fmaf(Wk[(size_t)(j + 3) * DD + d], bq[j + 3], a3);
    }
    u3[d] = (a0 + a1) + (a2 + a3);
  } else {
    const int j = b - 11780;
    float acc = 0.f;
    for (int d = tid; d < DD; d += 256) acc = fmaf(Wo[(size_t)j * DD + d], bv[d], acc);
#pragma unroll
    for (int off = 32; off >= 1; off >>= 1) acc += __shfl_down(acc, off);
    __shared__ float p[4];
    if ((tid & 63) == 0) p[tid >> 6] = acc;
    __syncthreads();
    if (tid == 0) bfin[j] = p[0] + p[1] + p[2] + p[3] + bo[j];
  }
}

// ---------- batched 64x64-tile GEMM for the two 1024^3 weight products ----------
__global__ __launch_bounds__(256) void k_gemm64x2(const short* __restrict__ WkT,
                                                  const short* __restrict__ WqT,
                                                  short* __restrict__ A2,
                                                  const short* __restrict__ WoB,
                                                  const short* __restrict__ WvT,
                                                  short* __restrict__ WB) {
  __shared__ short At[64 * 32];
  __shared__ short Bt[64 * 32];
  const short* A; const short* B; short* C; int lda, ldb, ldc;
  if (blockIdx.z == 0) {
    A = WkT; lda = 1024; B = WqT; ldb = 1024; C = A2; ldc = 1024;
  } else {
    A = WoB; lda = 2048; B = WvT; ldb = 1024; C = WB; ldc = 2048;
  }
  const int tid = threadIdx.x;
  const int w = tid >> 6, l = tid & 63;
  const int wm = w >> 1, wn = w & 1;
  const int lrow = l & 15, lk = l >> 4;
  const size_t m0 = (size_t)blockIdx.x * 64;
  const size_t n0 = (size_t)blockIdx.y * 64;

  f32x4 acc[2][2];
#pragma unroll
  for (int i = 0; i < 2; i++)
#pragma unroll
    for (int j = 0; j < 2; j++) acc[i][j] = (f32x4){0.f, 0.f, 0.f, 0.f};

  const unsigned ubase = (unsigned)((tid & ~63) * 16);
  const int r0 = tid >> 2, kc = tid & 3;

  for (int k0 = 0; k0 < 1024; k0 += 32) {
    __syncthreads();
    gload_lds16(A + (m0 + r0) * lda + k0 + kc * 8, (char*)At + ubase);
    gload_lds16(B + (n0 + r0) * ldb + k0 + kc * 8, (char*)Bt + ubase);
    __syncthreads();
    short8 af[2], bfv[2];
    const int aoff = (wm * 32 + lrow) * 32 + lk * 8;
    const int boff = (wn * 32 + lrow) * 32 + lk * 8;
#pragma unroll
    for (int mi = 0; mi < 2; mi++) af[mi] = *(const short8*)(At + aoff + mi * 512);
#pragma unroll
    for (int ni = 0; ni < 2; ni++) bfv[ni] = *(const short8*)(Bt + boff + ni * 512);
#pragma unroll
    for (int mi = 0; mi < 2; mi++)
#pragma unroll
      for (int ni = 0; ni < 2; ni++)
        acc[mi][ni] = __builtin_amdgcn_mfma_f32_16x16x32_bf16(af[mi], bfv[ni],
                                                              acc[mi][ni], 0, 0, 0);
  }

#pragma unroll
  for (int ni = 0; ni < 2; ni++) {
    const size_t col = n0 + wn * 32 + ni * 16 + lrow;
#pragma unroll
    for (int mi = 0; mi < 2; mi++) {
#pragma unroll
      for (int q = 0; q < 4; q++) {
        const size_t row = m0 + wm * 32 + mi * 16 + lk * 4 + q;
        C[row * ldc + col] = f2b(acc[mi][ni][q]);
      }
    }
  }
}

// ---------- 128x128 / BK=64, 4 waves (2x2), st_16x32 swizzle, counted vmcnt ----
// LDS 80KB (-> 2 blocks/CU): A ring 3x16KB at 0, B ring 2x16KB at +48KB.
// Stage at tile top: B(t+1), A(t+2). Boundary: vmcnt(4) (A(t+2) may stay in
// flight; in-order => A(t+1),B(t+1) drained) + one s_barrier per K-tile.
// Cross-block wave overlap (2 blocks/CU) hides the boundary bubble.
template <bool OUT_BF16>
__global__ __launch_bounds__(256) void k_gemm128(const short* __restrict__ A, int lda,
                                                 const short* __restrict__ B, int ldb,
                                                 void* __restrict__ Cv, int ldc, int K,
                                                 const float* __restrict__ bias,
                                                 int nblocks) {
  extern __shared__ char lds[];
  char* ldsA = lds;            // 3 x 16KB
  char* ldsB = lds + 49152;    // 2 x 16KB
  const int tid = threadIdx.x;
  const int w = tid >> 6;
  const int l = tid & 63;
  const int wm = w >> 1, wn = w & 1;
  const int lrow = l & 15, lk = l >> 4;

  // XCD-aware swizzle (gridDim.x % 8 == 0); nb fast within each XCD's chunk
  const int nwg = gridDim.x;
  const int cpx = nwg >> 3;
  const int lin = blockIdx.x;
  const int wg = (lin & 7) * cpx + (lin >> 3);
  const int mb = wg / nblocks;
  const int nb = wg % nblocks;
  const size_t m0 = (size_t)mb * 128;
  const size_t n0 = (size_t)nb * 128;

  // staging decode: physical q = j*4096 + tid*16 -> logical = q ^ ((q>>9&1)<<5)
  const int r = tid >> 3;  // 0..31
  const int kk0 = (((tid & 7) * 16) ^ (((tid >> 5) & 1) << 5)) >> 1;
  const short* pA0 = A + (m0 + r) * lda + kk0;
  const short* pA1 = A + (m0 + 32 + r) * lda + kk0;
  const short* pA2 = A + (m0 + 64 + r) * lda + kk0;
  const short* pA3 = A + (m0 + 96 + r) * lda + kk0;
  const short* pB0 = B + (n0 + r) * ldb + kk0;
  const short* pB1 = B + (n0 + 32 + r) * ldb + kk0;
  const short* pB2 = B + (n0 + 64 + r) * ldb + kk0;
  const short* pB3 = B + (n0 + 96 + r) * ldb + kk0;
  const unsigned wb16 = (unsigned)((tid & ~63) * 16);

  f32x4 acc[4][4];
#pragma unroll
  for (int i = 0; i < 4; i++)
#pragma unroll
    for (int j = 0; j < 4; j++) acc[i][j] = (f32x4){0.f, 0.f, 0.f, 0.f};

  const int NT = K >> 6;

#define STAGE_A(bufsel, koff)                                     \
  do {                                                            \
    char* ab_ = ldsA + (bufsel) * 16384;                          \
    gload_lds16(pA0 + (koff), ab_ + wb16);                        \
    gload_lds16(pA1 + (koff), ab_ + 4096 + wb16);                 \
    gload_lds16(pA2 + (koff), ab_ + 8192 + wb16);                 \
    gload_lds16(pA3 + (koff), ab_ + 12288 + wb16);                \
  } while (0)
#define STAGE_B(bufsel, koff)                                     \
  do {                                                            \
    char* bb_ = ldsB + (bufsel) * 16384;                          \
    gload_lds16(pB0 + (koff), bb_ + wb16);                        \
    gload_lds16(pB1 + (koff), bb_ + 4096 + wb16);                 \
    gload_lds16(pB2 + (koff), bb_ + 8192 + wb16);                 \
    gload_lds16(pB3 + (koff), bb_ + 12288 + wb16);                \
  } while (0)

  // prologue: B0, A0, A1 in flight; wait for B0,A0 (allow A1 outstanding)
  STAGE_B(0, 0);
  STAGE_A(0, 0);
  if (NT > 1) {
    STAGE_A(1, 64);
    asm volatile("s_waitcnt vmcnt(4)" ::: "memory");
  } else {
    asm volatile("s_waitcnt vmcnt(0)" ::: "memory");
  }
  __builtin_amdgcn_s_barrier();
  __builtin_amdgcn_sched_barrier(0);

  const int aswz = ((lrow >> 2) & 1) << 5;  // st_16x32: flip bit5 when row bit2 set

  for (int kt = 0; kt < NT; ++kt) {
    const char* Ab = ldsA + (kt % 3) * 16384;
    const char* Bb = ldsB + (kt & 1) * 16384;

    // issue next-tile staging first; it completes under this tile's compute
    if (kt + 1 < NT) STAGE_B((kt + 1) & 1, (size_t)(kt + 1) * 64);
    if (kt + 2 < NT) STAGE_A((kt + 2) % 3, (size_t)(kt + 2) * 64);

    short8 bfr[4][2];
#pragma unroll
    for (int ni = 0; ni < 4; ni++)
#pragma unroll
      for (int ks = 0; ks < 2; ks++) {
        const int ph =
            (((wn * 64 + ni * 16 + lrow) * 128 + ks * 64 + lk * 16)) ^ aswz;
        bfr[ni][ks] = *(const short8*)(Bb + ph);
      }
    short8 af[4][2];
#pragma unroll
    for (int mi = 0; mi < 4; mi++)
#pragma unroll
      for (int ks = 0; ks < 2; ks++) {
        const int ph =
            (((wm * 64 + mi * 16 + lrow) * 128 + ks * 64 + lk * 16)) ^ aswz;
        af[mi][ks] = *(const short8*)(Ab + ph);
      }
#pragma unroll
    for (int ks = 0; ks < 2; ks++)
#pragma unroll
      for (int mi = 0; mi < 4; mi++)
#pragma unroll
        for (int ni = 0; ni < 4; ni++)
          acc[mi][ni] = __builtin_amdgcn_mfma_f32_16x16x32_bf16(
              af[mi][ks], bfr[ni][ks], acc[mi][ni], 0, 0, 0);

    if (kt + 1 < NT) {
      if (kt + 2 < NT)
        asm volatile("s_waitcnt vmcnt(4)" ::: "memory");
      else
        asm volatile("s_waitcnt vmcnt(0)" ::: "memory");
      __builtin_amdgcn_s_barrier();
      __builtin_amdgcn_sched_barrier(0);
    }
  }
#undef STAGE_A
#undef STAGE_B

#pragma unroll
  for (int ni = 0; ni < 4; ni++) {
    const size_t col = n0 + wn * 64 + ni * 16 + lrow;
    const float bv_ = bias ? bias[col] : 0.f;
#pragma unroll
    for (int mi = 0; mi < 4; mi++) {
#pragma unroll
      for (int q = 0; q < 4; q++) {
        const size_t row = m0 + wm * 64 + mi * 16 + lk * 4 + q;
        const float v = acc[mi][ni][q] + bv_;
        if (OUT_BF16)
          ((short*)Cv)[row * ldc + col] = f2b(v);
        else
          ((float*)Cv)[row * ldc + col] = v;
      }
    }
  }
}

// ---------- fused scores + softmax + AH, one block per position t ----------
// histT: [d][slot][8] bf16 where slot = (h>>3) ^ ((d>>1)&3)  (16B-slot swizzle).
__global__ __launch_bounds__(512) void k_fused(const short* __restrict__ xA,
                                               const float* __restrict__ hist,
                                               const float* __restrict__ u3,
                                               const float* __restrict__ decay,
                                               short* __restrict__ CC) {
  extern __shared__ char smem[];
  short* histT = (short*)smem;                         // [1024][32] bf16, 64KB
  float* spart = (float*)(smem + 65536);               // [4][16][32] f32, 8KB
  float* sfull = (float*)(smem + 65536 + 8192);        // [16][32] f32, 2KB
  short* attnb = (short*)(smem + 65536 + 8192 + 2048); // [16][32] bf16, 1KB

  const int t = blockIdx.x;
  const int tid = threadIdx.x;
  const int w = tid >> 6, l = tid & 63;
  const int lrow = l & 15, lk = l >> 4;

  f32x4 accs[2];
  accs[0] = (f32x4){0.f, 0.f, 0.f, 0.f};
  accs[1] = (f32x4){0.f, 0.f, 0.f, 0.f};

#pragma unroll
  for (int kk = 0; kk < 4; kk++) {
    const int ka = (w * 4 + kk) * 32 + lk * 8;
    short8 af;
    if (lrow < 8) {
      af = *(const short8*)(xA + ((size_t)lrow * TT + t) * DD + ka);
    } else if (lrow == 8) {
      const float* up = u3 + ka;
#pragma unroll
      for (int j = 0; j < 8; j++) af[j] = f2b(up[j]);
    } else {
#pragma unroll
      for (int j = 0; j < 8; j++) af[j] = 0;
    }
#pragma unroll
    for (int nt = 0; nt < 2; nt++) {
      const int h = lrow + nt * 16;
      const float* hp = hist + ((size_t)t * HH + h) * DD + ka;
      float4 h0 = *(const float4*)hp;
      float4 h1 = *(const float4*)(hp + 4);
      short8 bv_;
      bv_[0] = f2b(h0.x); bv_[1] = f2b(h0.y); bv_[2] = f2b(h0.z); bv_[3] = f2b(h0.w);
      bv_[4] = f2b(h1.x); bv_[5] = f2b(h1.y); bv_[6] = f2b(h1.z); bv_[7] = f2b(h1.w);
      accs[nt] = __builtin_amdgcn_mfma_f32_16x16x32_bf16(af, bv_, accs[nt], 0, 0, 0);
      const int hs = h >> 3, hl = h & 7;
#pragma unroll
      for (int j = 0; j < 8; j++) {
        const int d = ka + j;
        histT[(d << 5) + ((hs ^ ((d >> 1) & 3)) << 3) + hl] = bv_[j];
      }
    }
  }

  // deterministic cross-wave score reduction (8 -> 1)
  for (int half = 4; half >= 1; half >>= 1) {
    __syncthreads();
    if (w >= half && w < 2 * half) {
#pragma unroll
      for (int nt = 0; nt < 2; nt++)
#pragma unroll
        for (int q = 0; q < 4; q++)
          spart[(w - half) * 512 + (lk * 4 + q) * 32 + nt * 16 + lrow] = accs[nt][q];
    }
    __syncthreads();
    if (w < half) {
#pragma unroll
      for (int nt = 0; nt < 2; nt++)
#pragma unroll
        for (int q = 0; q < 4; q++)
          accs[nt][q] += spart[w * 512 + (lk * 4 + q) * 32 + nt * 16 + lrow];
    }
  }
  if (w == 0) {
#pragma unroll
    for (int nt = 0; nt < 2; nt++)
#pragma unroll
      for (int q = 0; q < 4; q++)
        sfull[(lk * 4 + q) * 32 + nt * 16 + lrow] = accs[nt][q];
  }
  __syncthreads();

  // softmax over h within 32-thread groups (b = tid>>5)
  {
    const int bb = tid >> 5, h = tid & 31;
    float s = (sfull[bb * 32 + h] + sfull[8 * 32 + h]) * (1.0f / 32.0f) +
              logf(decay[31 - h] + 1e-10f);
    float m = s;
#pragma unroll
    for (int msk = 16; msk >= 1; msk >>= 1) m = fmaxf(m, __shfl_xor(m, msk));
    float p = expf(s - m);
    float den = p;
#pragma unroll
    for (int msk = 16; msk >= 1; msk >>= 1) den += __shfl_xor(den, msk);
    attnb[bb * 32 + h] = f2b(p / den);
  }
  __syncthreads();

  // phase 3: AH[b,d] = sum_h attn[b,h]*hist[h,d]; wave w covers d in [w*128,(w+1)*128)
  short8 paf = *(const short8*)(attnb + lrow * 32 + lk * 8);
  const f32x4 z4 = (f32x4){0.f, 0.f, 0.f, 0.f};
#pragma unroll
  for (int i = 0; i < 8; i++) {
    const int d0 = (w * 8 + i) * 16;
    const int d = d0 + lrow;
    short8 hb = *(const short8*)(histT + (d << 5) + ((lk ^ ((d >> 1) & 3)) << 3));
    f32x4 o = __builtin_amdgcn_mfma_f32_16x16x32_bf16(paf, hb, z4, 0, 0, 0);
    if (lk < 2) {
#pragma unroll
      for (int q = 0; q < 4; q++) {
        const int b = lk * 4 + q;
        CC[((size_t)b * TT + t) * 2048 + d0 + lrow] = f2b(o[q]);
      }
    }
  }
}

extern "C" void kernel_launch(void* const* d_in, const int* in_sizes, int n_in,
                              void* d_out, int out_size, void* d_ws, size_t ws_size,
                              hipStream_t stream) {
  (void)in_sizes; (void)n_in; (void)out_size; (void)ws_size;
  const float* x    = (const float*)d_in[0];
  const float* hist = (const float*)d_in[1];
  const float* Wq   = (const float*)d_in[2];
  const float* bq   = (const float*)d_in[3];
  const float* Wk   = (const float*)d_in[4];
  // d_in[5] = bk: h-constant in scores -> softmax-invariant, dropped exactly.
  const float* Wv   = (const float*)d_in[6];
  const float* bv   = (const float*)d_in[7];
  const float* Wo   = (const float*)d_in[8];
  const float* bo   = (const float*)d_in[9];
  const float* dec  = (const float*)d_in[10];
  float* out = (float*)d_out;
  char* ws = (char*)d_ws;

  short* CC   = (short*)(ws + 0);          // [16384][2048] bf16: [AH | x]
  short* xA   = (short*)(ws + 67108864);   // [16384][1024] bf16
  short* A2   = (short*)(ws + 100663296);  // [1024][1024] bf16 = Wk^T Wq
  short* WB   = (short*)(ws + 102760448);  // [1024][2048] bf16: [Wvo | Wo]
  short* WqT  = (short*)(ws + 106954752);
  short* WkT  = (short*)(ws + 109051904);
  short* WvT  = (short*)(ws + 111149056);
  float* bfin = (float*)(ws + 113246208);
  float* u3   = (float*)(ws + 113250304);

  hipFuncSetAttribute((const void*)k_fused, hipFuncAttributeMaxDynamicSharedMemorySize,
                      76800);
  hipFuncSetAttribute((const void*)k_gemm128<true>,
                      hipFuncAttributeMaxDynamicSharedMemorySize, 81920);
  hipFuncSetAttribute((const void*)k_gemm128<false>,
                      hipFuncAttributeMaxDynamicSharedMemorySize, 81920);

  // all prep in one launch
  k_prep<<<12804, 256, 0, stream>>>(x, Wq, bq, Wk, Wv, bv, Wo, bo, WqT, WkT, WvT, CC,
                                    WB, u3, bfin);
  // A2 = Wk^T Wq  and  Wvo = Wo*Wv (into WB left half), batched
  k_gemm64x2<<<dim3(16, 16, 2), 256, 0, stream>>>(WkT, WqT, A2, WB + 1024, WvT, WB);
  // xA = x_bf16 * A2^T   (M=16384, N=1024 -> 1024 blocks, 8 n-blocks)
  k_gemm128<true><<<1024, 256, 81920, stream>>>(CC + 1024, 2048, A2, 1024, xA, 1024,
                                                1024, nullptr, 8);
  // fused scores/softmax/AH -> CC left half
  k_fused<<<2048, 512, 76800, stream>>>(xA, hist, u3, dec, CC);
  // out = [AH|x] * [Wvo|Wo]^T + bfinal   (M=16384, N=1024, K=2048 -> 1024 blocks)
  k_gemm128<false><<<1024, 256, 81920, stream>>>(CC, 2048, WB, 2048, out, 1024, 2048,
                                                 bfin, 8);
}

// Round 9
// 259.737 us; speedup vs baseline: 1.1123x; 1.0248x over previous
//
#include <hip/hip_runtime.h>

// HistoryAttention, restructured:
//   A2  = Wk^T Wq                  (so xA = x@(Wq^T Wk) = x · A2^T)
//   xA  = x_bf16 · A2^T            [16384,1024]
//   scores[b,t,h] = (xA[b,t]·hist[t,h] + hist[t,h]·u3)/32 + log(decay[31-h]+1e-10)
//   AH[b,t] = sum_h softmax(scores)·hist[t,h]
//   out = [AH | x] · [Wvo | Wo]^T + (Wo·bv + bo),  Wvo = Wo·Wv
// Big GEMMs: 128x128/BK=64, 4 waves, A 3-ring + B 2-ring (80KB -> 2 blocks/CU),
// one counted-vmcnt barrier per K-tile, stages interleaved with ds_reads.
// k_fused: coalesced AH store via LDS bounce (reuses histT after reads drain).

#define BB 8
#define TT 2048
#define DD 1024
#define HH 32

typedef __attribute__((ext_vector_type(8))) short short8;
typedef __attribute__((ext_vector_type(4))) float f32x4;

__device__ __forceinline__ short f2b(float f) {
  unsigned u = __float_as_uint(f);
  unsigned r = u + 0x7fffu + ((u >> 16) & 1u);
  return (short)(r >> 16);
}

__device__ __forceinline__ void gload_lds16(const void* g, void* l) {
  __builtin_amdgcn_global_load_lds(
      (const __attribute__((address_space(1))) void*)g,
      (__attribute__((address_space(3))) void*)l, 16, 0, 0);
}

// ---------- fused prep: weight transposes, bf16 converts, u3, bfinal ----------
__global__ __launch_bounds__(256) void k_prep(
    const float* __restrict__ x, const float* __restrict__ Wq,
    const float* __restrict__ bq, const float* __restrict__ Wk,
    const float* __restrict__ Wv, const float* __restrict__ bv,
    const float* __restrict__ Wo, const float* __restrict__ bo,
    short* __restrict__ WqT, short* __restrict__ WkT, short* __restrict__ WvT,
    short* __restrict__ CC, short* __restrict__ WB, float* __restrict__ u3,
    float* __restrict__ bfin) {
  const int b = blockIdx.x;
  const int tid = threadIdx.x;
  if (b < 3072) {
    __shared__ float tile[32][33];
    const int z = b >> 10, rem = b & 1023;
    const float* src = z == 0 ? Wq : (z == 1 ? Wk : Wv);
    short* dst = z == 0 ? WqT : (z == 1 ? WkT : WvT);
    const int bx = (rem & 31) * 32, by = (rem >> 5) * 32;
    const int tx = tid & 31, ty = tid >> 5;
#pragma unroll
    for (int k = 0; k < 4; k++)
      tile[ty + 8 * k][tx] = src[(size_t)(by + ty + 8 * k) * DD + bx + tx];
    __syncthreads();
#pragma unroll
    for (int k = 0; k < 4; k++)
      dst[(size_t)(bx + ty + 8 * k) * DD + by + tx] = f2b(tile[tx][ty + 8 * k]);
  } else if (b < 11776) {
    const bool isx = b < 11264;
    const float* src = isx ? x : Wo;
    short* dst = isx ? CC : WB;
    size_t i = (((size_t)(b - (isx ? 3072 : 11264))) * 256 + tid) * 8;
    float4 a = *(const float4*)(src + i);
    float4 c = *(const float4*)(src + i + 4);
    short8 o;
    o[0] = f2b(a.x); o[1] = f2b(a.y); o[2] = f2b(a.z); o[3] = f2b(a.w);
    o[4] = f2b(c.x); o[5] = f2b(c.y); o[6] = f2b(c.z); o[7] = f2b(c.w);
    size_t r = i >> 10, cc = i & 1023;
    *(short8*)(dst + r * 2048 + 1024 + cc) = o;
  } else if (b < 11780) {
    const int d = (b - 11776) * 256 + tid;
    float a0 = 0, a1 = 0, a2 = 0, a3 = 0;
    for (int j = 0; j < DD; j += 4) {
      a0 = fmaf(Wk[(size_t)(j + 0) * DD + d], bq[j + 0], a0);
      a1 = fmaf(Wk[(size_t)(j + 1) * DD + d], bq[j + 1], a1);
      a2 = fmaf(Wk[(size_t)(j + 2) * DD + d], bq[j + 2], a2);
      a3 = fmaf(Wk[(size_t)(j + 3) * DD + d], bq[j + 3], a3);
    }
    u3[d] = (a0 + a1) + (a2 + a3);
  } else {
    const int j = b - 11780;
    float acc = 0.f;
    for (int d = tid; d < DD; d += 256) acc = fmaf(Wo[(size_t)j * DD + d], bv[d], acc);
#pragma unroll
    for (int off = 32; off >= 1; off >>= 1) acc += __shfl_down(acc, off);
    __shared__ float p[4];
    if ((tid & 63) == 0) p[tid >> 6] = acc;
    __syncthreads();
    if (tid == 0) bfin[j] = p[0] + p[1] + p[2] + p[3] + bo[j];
  }
}

// ---------- batched 64x64-tile GEMM for the two 1024^3 weight products ----------
__global__ __launch_bounds__(256) void k_gemm64x2(const short* __restrict__ WkT,
                                                  const short* __restrict__ WqT,
                                                  short* __restrict__ A2,
                                                  const short* __restrict__ WoB,
                                                  const short* __restrict__ WvT,
                                                  short* __restrict__ WB) {
  __shared__ short At[64 * 32];
  __shared__ short Bt[64 * 32];
  const short* A; const short* B; short* C; int lda, ldb, ldc;
  if (blockIdx.z == 0) {
    A = WkT; lda = 1024; B = WqT; ldb = 1024; C = A2; ldc = 1024;
  } else {
    A = WoB; lda = 2048; B = WvT; ldb = 1024; C = WB; ldc = 2048;
  }
  const int tid = threadIdx.x;
  const int w = tid >> 6, l = tid & 63;
  const int wm = w >> 1, wn = w & 1;
  const int lrow = l & 15, lk = l >> 4;
  const size_t m0 = (size_t)blockIdx.x * 64;
  const size_t n0 = (size_t)blockIdx.y * 64;

  f32x4 acc[2][2];
#pragma unroll
  for (int i = 0; i < 2; i++)
#pragma unroll
    for (int j = 0; j < 2; j++) acc[i][j] = (f32x4){0.f, 0.f, 0.f, 0.f};

  const unsigned ubase = (unsigned)((tid & ~63) * 16);
  const int r0 = tid >> 2, kc = tid & 3;

  for (int k0 = 0; k0 < 1024; k0 += 32) {
    __syncthreads();
    gload_lds16(A + (m0 + r0) * lda + k0 + kc * 8, (char*)At + ubase);
    gload_lds16(B + (n0 + r0) * ldb + k0 + kc * 8, (char*)Bt + ubase);
    __syncthreads();
    short8 af[2], bfv[2];
    const int aoff = (wm * 32 + lrow) * 32 + lk * 8;
    const int boff = (wn * 32 + lrow) * 32 + lk * 8;
#pragma unroll
    for (int mi = 0; mi < 2; mi++) af[mi] = *(const short8*)(At + aoff + mi * 512);
#pragma unroll
    for (int ni = 0; ni < 2; ni++) bfv[ni] = *(const short8*)(Bt + boff + ni * 512);
#pragma unroll
    for (int mi = 0; mi < 2; mi++)
#pragma unroll
      for (int ni = 0; ni < 2; ni++)
        acc[mi][ni] = __builtin_amdgcn_mfma_f32_16x16x32_bf16(af[mi], bfv[ni],
                                                              acc[mi][ni], 0, 0, 0);
  }

#pragma unroll
  for (int ni = 0; ni < 2; ni++) {
    const size_t col = n0 + wn * 32 + ni * 16 + lrow;
#pragma unroll
    for (int mi = 0; mi < 2; mi++) {
#pragma unroll
      for (int q = 0; q < 4; q++) {
        const size_t row = m0 + wm * 32 + mi * 16 + lk * 4 + q;
        C[row * ldc + col] = f2b(acc[mi][ni][q]);
      }
    }
  }
}

// ---------- 128x128 / BK=64, 4 waves (2x2), st_16x32 swizzle, counted vmcnt ----
// LDS 80KB (-> 2 blocks/CU): A ring 3x16KB at 0, B ring 2x16KB at +48KB.
// Stages interleaved with ds_reads (B after bfr, A after af). Boundary:
// vmcnt(4) + one s_barrier per K-tile. Cross-block overlap hides the bubble.
template <bool OUT_BF16>
__global__ __launch_bounds__(256) void k_gemm128(const short* __restrict__ A, int lda,
                                                 const short* __restrict__ B, int ldb,
                                                 void* __restrict__ Cv, int ldc, int K,
                                                 const float* __restrict__ bias,
                                                 int nblocks) {
  extern __shared__ char lds[];
  char* ldsA = lds;            // 3 x 16KB
  char* ldsB = lds + 49152;    // 2 x 16KB
  const int tid = threadIdx.x;
  const int w = tid >> 6;
  const int l = tid & 63;
  const int wm = w >> 1, wn = w & 1;
  const int lrow = l & 15, lk = l >> 4;

  // XCD-aware swizzle (gridDim.x % 8 == 0); nb fast within each XCD's chunk
  const int nwg = gridDim.x;
  const int cpx = nwg >> 3;
  const int lin = blockIdx.x;
  const int wg = (lin & 7) * cpx + (lin >> 3);
  const int mb = wg / nblocks;
  const int nb = wg % nblocks;
  const size_t m0 = (size_t)mb * 128;
  const size_t n0 = (size_t)nb * 128;

  // staging decode: physical q = j*4096 + tid*16 -> logical = q ^ ((q>>9&1)<<5)
  const int r = tid >> 3;  // 0..31
  const int kk0 = (((tid & 7) * 16) ^ (((tid >> 5) & 1) << 5)) >> 1;
  const short* pA0 = A + (m0 + r) * lda + kk0;
  const short* pA1 = A + (m0 + 32 + r) * lda + kk0;
  const short* pA2 = A + (m0 + 64 + r) * lda + kk0;
  const short* pA3 = A + (m0 + 96 + r) * lda + kk0;
  const short* pB0 = B + (n0 + r) * ldb + kk0;
  const short* pB1 = B + (n0 + 32 + r) * ldb + kk0;
  const short* pB2 = B + (n0 + 64 + r) * ldb + kk0;
  const short* pB3 = B + (n0 + 96 + r) * ldb + kk0;
  const unsigned wb16 = (unsigned)((tid & ~63) * 16);

  f32x4 acc[4][4];
#pragma unroll
  for (int i = 0; i < 4; i++)
#pragma unroll
    for (int j = 0; j < 4; j++) acc[i][j] = (f32x4){0.f, 0.f, 0.f, 0.f};

  const int NT = K >> 6;

#define STAGE_A(bufsel, koff)                                     \
  do {                                                            \
    char* ab_ = ldsA + (bufsel) * 16384;                          \
    gload_lds16(pA0 + (koff), ab_ + wb16);                        \
    gload_lds16(pA1 + (koff), ab_ + 4096 + wb16);                 \
    gload_lds16(pA2 + (koff), ab_ + 8192 + wb16);                 \
    gload_lds16(pA3 + (koff), ab_ + 12288 + wb16);                \
  } while (0)
#define STAGE_B(bufsel, koff)                                     \
  do {                                                            \
    char* bb_ = ldsB + (bufsel) * 16384;                          \
    gload_lds16(pB0 + (koff), bb_ + wb16);                        \
    gload_lds16(pB1 + (koff), bb_ + 4096 + wb16);                 \
    gload_lds16(pB2 + (koff), bb_ + 8192 + wb16);                 \
    gload_lds16(pB3 + (koff), bb_ + 12288 + wb16);                \
  } while (0)

  // prologue: B0, A0, A1 in flight; wait for B0,A0 (allow A1 outstanding)
  STAGE_B(0, 0);
  STAGE_A(0, 0);
  if (NT > 1) {
    STAGE_A(1, 64);
    asm volatile("s_waitcnt vmcnt(4)" ::: "memory");
  } else {
    asm volatile("s_waitcnt vmcnt(0)" ::: "memory");
  }
  __builtin_amdgcn_s_barrier();
  __builtin_amdgcn_sched_barrier(0);

  const int aswz = ((lrow >> 2) & 1) << 5;  // st_16x32: flip bit5 when row bit2 set

  for (int kt = 0; kt < NT; ++kt) {
    const char* Ab = ldsA + (kt % 3) * 16384;
    const char* Bb = ldsB + (kt & 1) * 16384;

    short8 bfr[4][2];
#pragma unroll
    for (int ni = 0; ni < 4; ni++)
#pragma unroll
      for (int ks = 0; ks < 2; ks++) {
        const int ph =
            (((wn * 64 + ni * 16 + lrow) * 128 + ks * 64 + lk * 16)) ^ aswz;
        bfr[ni][ks] = *(const short8*)(Bb + ph);
      }
    if (kt + 1 < NT) STAGE_B((kt + 1) & 1, (size_t)(kt + 1) * 64);

    short8 af[4][2];
#pragma unroll
    for (int mi = 0; mi < 4; mi++)
#pragma unroll
      for (int ks = 0; ks < 2; ks++) {
        const int ph =
            (((wm * 64 + mi * 16 + lrow) * 128 + ks * 64 + lk * 16)) ^ aswz;
        af[mi][ks] = *(const short8*)(Ab + ph);
      }
    if (kt + 2 < NT) STAGE_A((kt + 2) % 3, (size_t)(kt + 2) * 64);

#pragma unroll
    for (int ks = 0; ks < 2; ks++)
#pragma unroll
      for (int mi = 0; mi < 4; mi++)
#pragma unroll
        for (int ni = 0; ni < 4; ni++)
          acc[mi][ni] = __builtin_amdgcn_mfma_f32_16x16x32_bf16(
              af[mi][ks], bfr[ni][ks], acc[mi][ni], 0, 0, 0);

    if (kt + 1 < NT) {
      if (kt + 2 < NT)
        asm volatile("s_waitcnt vmcnt(4)" ::: "memory");
      else
        asm volatile("s_waitcnt vmcnt(0)" ::: "memory");
      __builtin_amdgcn_s_barrier();
      __builtin_amdgcn_sched_barrier(0);
    }
  }
#undef STAGE_A
#undef STAGE_B

#pragma unroll
  for (int ni = 0; ni < 4; ni++) {
    const size_t col = n0 + wn * 64 + ni * 16 + lrow;
    const float bv_ = bias ? bias[col] : 0.f;
#pragma unroll
    for (int mi = 0; mi < 4; mi++) {
#pragma unroll
      for (int q = 0; q < 4; q++) {
        const size_t row = m0 + wm * 64 + mi * 16 + lk * 4 + q;
        const float v = acc[mi][ni][q] + bv_;
        if (OUT_BF16)
          ((short*)Cv)[row * ldc + col] = f2b(v);
        else
          ((float*)Cv)[row * ldc + col] = v;
      }
    }
  }
}

// ---------- fused scores + softmax + AH, one block per position t ----------
// histT: [d][slot][8] bf16, slot = (h>>3) ^ ((d>>1)&3)  (16B-slot swizzle).
// AH epilogue: results in regs -> barrier -> LDS bounce (reuse histT) ->
// coalesced 2x16B stores per thread.
__global__ __launch_bounds__(512) void k_fused(const short* __restrict__ xA,
                                               const float* __restrict__ hist,
                                               const float* __restrict__ u3,
                                               const float* __restrict__ decay,
                                               short* __restrict__ CC) {
  extern __shared__ char smem[];
  short* histT = (short*)smem;                         // [1024][32] bf16, 64KB
  float* spart = (float*)(smem + 65536);               // [4][16][32] f32, 8KB
  float* sfull = (float*)(smem + 65536 + 8192);        // [16][32] f32, 2KB
  short* attnb = (short*)(smem + 65536 + 8192 + 2048); // [16][32] bf16, 1KB

  const int t = blockIdx.x;
  const int tid = threadIdx.x;
  const int w = tid >> 6, l = tid & 63;
  const int lrow = l & 15, lk = l >> 4;

  f32x4 accs[2];
  accs[0] = (f32x4){0.f, 0.f, 0.f, 0.f};
  accs[1] = (f32x4){0.f, 0.f, 0.f, 0.f};

#pragma unroll
  for (int kk = 0; kk < 4; kk++) {
    const int ka = (w * 4 + kk) * 32 + lk * 8;
    short8 af;
    if (lrow < 8) {
      af = *(const short8*)(xA + ((size_t)lrow * TT + t) * DD + ka);
    } else if (lrow == 8) {
      const float* up = u3 + ka;
#pragma unroll
      for (int j = 0; j < 8; j++) af[j] = f2b(up[j]);
    } else {
#pragma unroll
      for (int j = 0; j < 8; j++) af[j] = 0;
    }
#pragma unroll
    for (int nt = 0; nt < 2; nt++) {
      const int h = lrow + nt * 16;
      const float* hp = hist + ((size_t)t * HH + h) * DD + ka;
      float4 h0 = *(const float4*)hp;
      float4 h1 = *(const float4*)(hp + 4);
      short8 bv_;
      bv_[0] = f2b(h0.x); bv_[1] = f2b(h0.y); bv_[2] = f2b(h0.z); bv_[3] = f2b(h0.w);
      bv_[4] = f2b(h1.x); bv_[5] = f2b(h1.y); bv_[6] = f2b(h1.z); bv_[7] = f2b(h1.w);
      accs[nt] = __builtin_amdgcn_mfma_f32_16x16x32_bf16(af, bv_, accs[nt], 0, 0, 0);
      const int hs = h >> 3, hl = h & 7;
#pragma unroll
      for (int j = 0; j < 8; j++) {
        const int d = ka + j;
        histT[(d << 5) + ((hs ^ ((d >> 1) & 3)) << 3) + hl] = bv_[j];
      }
    }
  }

  // deterministic cross-wave score reduction (8 -> 1)
  for (int half = 4; half >= 1; half >>= 1) {
    __syncthreads();
    if (w >= half && w < 2 * half) {
#pragma unroll
      for (int nt = 0; nt < 2; nt++)
#pragma unroll
        for (int q = 0; q < 4; q++)
          spart[(w - half) * 512 + (lk * 4 + q) * 32 + nt * 16 + lrow] = accs[nt][q];
    }
    __syncthreads();
    if (w < half) {
#pragma unroll
      for (int nt = 0; nt < 2; nt++)
#pragma unroll
        for (int q = 0; q < 4; q++)
          accs[nt][q] += spart[w * 512 + (lk * 4 + q) * 32 + nt * 16 + lrow];
    }
  }
  if (w == 0) {
#pragma unroll
    for (int nt = 0; nt < 2; nt++)
#pragma unroll
      for (int q = 0; q < 4; q++)
        sfull[(lk * 4 + q) * 32 + nt * 16 + lrow] = accs[nt][q];
  }
  __syncthreads();

  // softmax over h within 32-thread groups (b = tid>>5)
  {
    const int bb = tid >> 5, h = tid & 31;
    float s = (sfull[bb * 32 + h] + sfull[8 * 32 + h]) * (1.0f / 32.0f) +
              logf(decay[31 - h] + 1e-10f);
    float m = s;
#pragma unroll
    for (int msk = 16; msk >= 1; msk >>= 1) m = fmaxf(m, __shfl_xor(m, msk));
    float p = expf(s - m);
    float den = p;
#pragma unroll
    for (int msk = 16; msk >= 1; msk >>= 1) den += __shfl_xor(den, msk);
    attnb[bb * 32 + h] = f2b(p / den);
  }
  __syncthreads();

  // phase 3: AH[b,d] = sum_h attn[b,h]*hist[h,d]; wave w covers d in [w*128,(w+1)*128)
  short8 paf = *(const short8*)(attnb + lrow * 32 + lk * 8);
  const f32x4 z4 = (f32x4){0.f, 0.f, 0.f, 0.f};
  float res[8][4];
#pragma unroll
  for (int i = 0; i < 8; i++) {
    const int d0 = (w * 8 + i) * 16;
    const int d = d0 + lrow;
    short8 hb = *(const short8*)(histT + (d << 5) + ((lk ^ ((d >> 1) & 3)) << 3));
    f32x4 o = __builtin_amdgcn_mfma_f32_16x16x32_bf16(paf, hb, z4, 0, 0, 0);
#pragma unroll
    for (int q = 0; q < 4; q++) res[i][q] = o[q];
  }
  __syncthreads();  // all histT reads complete before reuse
  short* ah = histT;  // [8][1024] bf16 bounce buffer
  if (lk < 2) {
#pragma unroll
    for (int i = 0; i < 8; i++) {
      const int d = (w * 8 + i) * 16 + lrow;
#pragma unroll
      for (int q = 0; q < 4; q++) ah[(lk * 4 + q) * 1024 + d] = f2b(res[i][q]);
    }
  }
  __syncthreads();
  {
    const int b = tid >> 6, c0 = (tid & 63) * 16;
    short8 v0 = *(const short8*)(ah + b * 1024 + c0);
    short8 v1 = *(const short8*)(ah + b * 1024 + c0 + 8);
    short* dst = CC + ((size_t)b * TT + t) * 2048 + c0;
    *(short8*)dst = v0;
    *(short8*)(dst + 8) = v1;
  }
}

extern "C" void kernel_launch(void* const* d_in, const int* in_sizes, int n_in,
                              void* d_out, int out_size, void* d_ws, size_t ws_size,
                              hipStream_t stream) {
  (void)in_sizes; (void)n_in; (void)out_size; (void)ws_size;
  const float* x    = (const float*)d_in[0];
  const float* hist = (const float*)d_in[1];
  const float* Wq   = (const float*)d_in[2];
  const float* bq   = (const float*)d_in[3];
  const float* Wk   = (const float*)d_in[4];
  // d_in[5] = bk: h-constant in scores -> softmax-invariant, dropped exactly.
  const float* Wv   = (const float*)d_in[6];
  const float* bv   = (const float*)d_in[7];
  const float* Wo   = (const float*)d_in[8];
  const float* bo   = (const float*)d_in[9];
  const float* dec  = (const float*)d_in[10];
  float* out = (float*)d_out;
  char* ws = (char*)d_ws;

  short* CC   = (short*)(ws + 0);          // [16384][2048] bf16: [AH | x]
  short* xA   = (short*)(ws + 67108864);   // [16384][1024] bf16
  short* A2   = (short*)(ws + 100663296);  // [1024][1024] bf16 = Wk^T Wq
  short* WB   = (short*)(ws + 102760448);  // [1024][2048] bf16: [Wvo | Wo]
  short* WqT  = (short*)(ws + 106954752);
  short* WkT  = (short*)(ws + 109051904);
  short* WvT  = (short*)(ws + 111149056);
  float* bfin = (float*)(ws + 113246208);
  float* u3   = (float*)(ws + 113250304);

  hipFuncSetAttribute((const void*)k_fused, hipFuncAttributeMaxDynamicSharedMemorySize,
                      76800);
  hipFuncSetAttribute((const void*)k_gemm128<true>,
                      hipFuncAttributeMaxDynamicSharedMemorySize, 81920);
  hipFuncSetAttribute((const void*)k_gemm128<false>,
                      hipFuncAttributeMaxDynamicSharedMemorySize, 81920);

  // all prep in one launch
  k_prep<<<12804, 256, 0, stream>>>(x, Wq, bq, Wk, Wv, bv, Wo, bo, WqT, WkT, WvT, CC,
                                    WB, u3, bfin);
  // A2 = Wk^T Wq  and  Wvo = Wo*Wv (into WB left half), batched
  k_gemm64x2<<<dim3(16, 16, 2), 256, 0, stream>>>(WkT, WqT, A2, WB + 1024, WvT, WB);
  // xA = x_bf16 * A2^T   (M=16384, N=1024 -> 1024 blocks, 8 n-blocks)
  k_gemm128<true><<<1024, 256, 81920, stream>>>(CC + 1024, 2048, A2, 1024, xA, 1024,
                                                1024, nullptr, 8);
  // fused scores/softmax/AH -> CC left half
  k_fused<<<2048, 512, 76800, stream>>>(xA, hist, u3, dec, CC);
  // out = [AH|x] * [Wvo|Wo]^T + bfinal   (M=16384, N=1024, K=2048 -> 1024 blocks)
  k_gemm128<false><<<1024, 256, 81920, stream>>>(CC, 2048, WB, 2048, out, 1024, 2048,
                                                 bfin, 8);
}